// Round 8
// baseline (327.614 us; speedup 1.0000x reference)
//
#include <hip/hip_runtime.h>

typedef __bf16 bf16x4 __attribute__((ext_vector_type(4)));
typedef __bf16 bf16x8 __attribute__((ext_vector_type(8)));
typedef float floatx4 __attribute__((ext_vector_type(4)));

constexpr int Bc = 4, Hc = 8, Nc = 2048, Dc = 64;
constexpr int BQ = 128;      // q-rows per block
constexpr int WQ = 32;       // q-rows per wave
constexpr int TK = 64;       // keys per tile
constexpr int NT = Nc / TK;  // 32 tiles
constexpr int SPS = 72;      // sP row stride (bf16)
constexpr float LOG2E = 1.44269504088896340736f;

// ws layout:
//   Ksw: [bh][jt] 8 KiB image, chunk g = key*8 + (kc ^ (key&7)) = K[key][kc*8..+7] bf16
//   Vsw: [bh][jt] 8 KiB image, chunk g = d*8   + (kc ^ (d&7))   = V^T[d][kc*8..+7] bf16
//   kkn: [bh][key] fp32 = -(sum K^2)*0.125*log2e
//   tickets (512 uint) + per-block partials (8192 O + 128 l fp32) for split-K
constexpr size_t KSW_OFF    = 0;
constexpr size_t VSW_OFF    = (size_t)32 * NT * 8192;        // 8 MiB
constexpr size_t KKN_OFF    = VSW_OFF * 2;                   // 16 MiB
constexpr size_t TICKET_OFF = (size_t)17 * 1024 * 1024;
constexpr size_t PART_OFF   = TICKET_OFF + 4096;
constexpr size_t PART_STRIDE = 33280;                        // bytes per partial blob
constexpr size_t WS_NEED    = PART_OFF + (size_t)1024 * PART_STRIDE;  // ~50.6 MB

typedef __attribute__((address_space(1))) const unsigned int gu32;
typedef __attribute__((address_space(3))) unsigned int lu32;
__device__ __forceinline__ void dma16(const void* g, void* l) {
    __builtin_amdgcn_global_load_lds((gu32*)g, (lu32*)l, 16, 0, 0);
}
__device__ __forceinline__ void dma4(const void* g, void* l) {
    __builtin_amdgcn_global_load_lds((gu32*)g, (lu32*)l, 4, 0, 0);
}

// ---------------- prep v2 (verified round 5): fully-coalesced image builder ----------------
__global__ __launch_bounds__(256) void prep_kernel(
    const float* __restrict__ Kg, const float* __restrict__ Vg, char* __restrict__ ws)
{
    __shared__ float sT[64 * 68];   // V tile [key][d], stride 68
    const int tid = threadIdx.x;
    const int jt = blockIdx.x, bh = blockIdx.y;

    __bf16* Ksw = (__bf16*)(ws + KSW_OFF) + ((size_t)bh * NT + jt) * 4096;
    __bf16* Vsw = (__bf16*)(ws + VSW_OFF) + ((size_t)bh * NT + jt) * 4096;
    float*  kkn = (float*)(ws + KKN_OFF) + (size_t)bh * Nc + jt * 64;
    const size_t tb = ((size_t)bh * Nc + jt * 64) * Dc;

#pragma unroll
    for (int cc = 0; cc < 2; ++cc) {
        const int g   = tid + cc * 256;
        const int key = g >> 3, kcx = g & 7;
        const int kc  = kcx ^ (key & 7);
        const float* src = Kg + tb + key * 64 + kc * 8;
        float4 a = *(const float4*)src;
        float4 b = *(const float4*)(src + 4);
        float ss = a.x*a.x + a.y*a.y + a.z*a.z + a.w*a.w
                 + b.x*b.x + b.y*b.y + b.z*b.z + b.w*b.w;
        ss += __shfl_xor(ss, 1);
        ss += __shfl_xor(ss, 2);
        ss += __shfl_xor(ss, 4);
        if (kcx == 0) kkn[key] = -(ss * 0.125f * LOG2E);
        bf16x8 c8;
        c8[0]=(__bf16)a.x; c8[1]=(__bf16)a.y; c8[2]=(__bf16)a.z; c8[3]=(__bf16)a.w;
        c8[4]=(__bf16)b.x; c8[5]=(__bf16)b.y; c8[6]=(__bf16)b.z; c8[7]=(__bf16)b.w;
        *(bf16x8*)(Ksw + g * 8) = c8;
    }
    {
        const int js = tid >> 2, dc = (tid & 3) * 16;
        const float* vr = Vg + tb + js * 64 + dc;
        float* dst = &sT[js * 68 + dc];
        *(float4*)dst       = *(const float4*)vr;
        *(float4*)(dst + 4) = *(const float4*)(vr + 4);
        *(float4*)(dst + 8) = *(const float4*)(vr + 8);
        *(float4*)(dst + 12)= *(const float4*)(vr + 12);
    }
    __syncthreads();
#pragma unroll
    for (int cc = 0; cc < 2; ++cc) {
        const int g = tid + cc * 256;
        const int d = g >> 3, kcx = g & 7;
        const int kc = kcx ^ (d & 7);
        bf16x8 c8;
#pragma unroll
        for (int e = 0; e < 8; ++e) {
            const int ee = (e + kcx) & 7;
            c8[ee] = (__bf16)sT[(kc * 8 + ee) * 68 + d];
        }
        *(bf16x8*)(Vsw + g * 8) = c8;
    }
}

// ---------------- main fused attention (round-3 body; optional block split-K) ----------------
// logits*log2e = (2qk - kk)/8*log2e; qq cancels. exp2-domain, no max-sub
// (bounded args). Q pre-scaled 0.25*log2e; -kk*log2e/8 is the acc init.
// split==2: blockIdx.z = key-half; partials combined via atomic ticket (the
// second finisher of each (bh,qt) pair reads partner's fp32 partial and stores).
__global__ __launch_bounds__(256, 2) void attn_kernel(
    const float* __restrict__ Qg, char* __restrict__ ws, float* __restrict__ Og,
    const int split)
{
    __shared__ __align__(16) __bf16 sK[2][4096];
    __shared__ __align__(16) __bf16 sV[2][4096];
    __shared__ __align__(16) float  skk[2][64];
    __shared__ __align__(16) __bf16 sP[BQ * SPS];
    __shared__ __align__(16) float  sl[BQ];
    __shared__ int sflag;

    const int tid  = threadIdx.x;
    const int wave = tid >> 6;
    const int lane = tid & 63;
    const int qd   = lane >> 4;
    const int c    = lane & 15;

    const int qt = blockIdx.x;    // 0..15
    const int bh = blockIdx.y;    // 0..31
    const int kh = blockIdx.z;    // 0..split-1

    const char* Kimg = ws + KSW_OFF + (size_t)bh * NT * 8192;
    const char* Vimg = ws + VSW_OFF + (size_t)bh * NT * 8192;
    const float* kkp = (const float*)(ws + KKN_OFF) + (size_t)bh * Nc;

    const float qscale = 0.25f * LOG2E;
    const int i0 = qt * BQ + wave * WQ;

    // Q fragments (B-operand): qf[h][ks] = Q[i0+h*16+c][ks*32+qd*8+j]*qscale
    bf16x8 qf[2][2];
#pragma unroll
    for (int h = 0; h < 2; ++h) {
        const float* qrow = Qg + ((size_t)bh * Nc + i0 + h * 16 + c) * Dc + qd * 8;
#pragma unroll
        for (int ks = 0; ks < 2; ++ks) {
            float4 a = *(const float4*)(qrow + ks * 32);
            float4 b = *(const float4*)(qrow + ks * 32 + 4);
            bf16x8 f;
            f[0] = (__bf16)(a.x * qscale); f[1] = (__bf16)(a.y * qscale);
            f[2] = (__bf16)(a.z * qscale); f[3] = (__bf16)(a.w * qscale);
            f[4] = (__bf16)(b.x * qscale); f[5] = (__bf16)(b.y * qscale);
            f[6] = (__bf16)(b.z * qscale); f[7] = (__bf16)(b.w * qscale);
            qf[h][ks] = f;
        }
    }

    // fragment elem offsets into an 8KiB image (same for sK and sV)
    const int koff0 = c * 64 + ((qd ^ (c & 7)) << 3);         // ks=0
    const int koff1 = c * 64 + (((4 + qd) ^ (c & 7)) << 3);   // ks=1

    floatx4 oacc[2][4];
#pragma unroll
    for (int h = 0; h < 2; ++h)
#pragma unroll
        for (int dt = 0; dt < 4; ++dt)
#pragma unroll
            for (int e = 0; e < 4; ++e) oacc[h][dt][e] = 0.f;
    float lp[2] = {0.f, 0.f};

    auto stage = [&](int jt2, int b) {
        const char* ki = Kimg + (size_t)jt2 * 8192;
        const char* vi = Vimg + (size_t)jt2 * 8192;
#pragma unroll
        for (int i = 0; i < 2; ++i) {
            const int off    = wave * 2048 + i * 1024 + lane * 16;
            const int ldsoff = wave * 2048 + i * 1024;
            dma16(ki + off, (char*)&sK[b][0] + ldsoff);
            dma16(vi + off, (char*)&sV[b][0] + ldsoff);
        }
        if (wave == 3) dma4(kkp + jt2 * 64 + lane, &skk[b][0]);
    };

    const int nth = NT / split;
    const int jt0 = kh * nth;
    stage(jt0, 0);

    for (int it = 0; it < nth; ++it) {
        const int b = it & 1;
        __syncthreads();                            // buf b staged; buf b^1 consumed
        if (it + 1 < nth) stage(jt0 + it + 1, b ^ 1);

        // S^T = K.Q^T with acc init = -kk*scale (bias folded in)
        floatx4 st[2][4];
#pragma unroll
        for (int kt = 0; kt < 4; ++kt) {
            floatx4 kkf = *(const floatx4*)&skk[b][kt * 16 + qd * 4];
            st[0][kt] = kkf; st[1][kt] = kkf;
        }
#pragma unroll
        for (int kt = 0; kt < 4; ++kt) {
            const __bf16* kbase = &sK[b][kt * 1024];
            bf16x8 kf0 = *(const bf16x8*)(kbase + koff0);
            bf16x8 kf1 = *(const bf16x8*)(kbase + koff1);
            st[0][kt] = __builtin_amdgcn_mfma_f32_16x16x32_bf16(kf0, qf[0][0], st[0][kt], 0, 0, 0);
            st[0][kt] = __builtin_amdgcn_mfma_f32_16x16x32_bf16(kf1, qf[0][1], st[0][kt], 0, 0, 0);
            st[1][kt] = __builtin_amdgcn_mfma_f32_16x16x32_bf16(kf0, qf[1][0], st[1][kt], 0, 0, 0);
            st[1][kt] = __builtin_amdgcn_mfma_f32_16x16x32_bf16(kf1, qf[1][1], st[1][kt], 0, 0, 0);
        }

        // p = exp2(st); accumulate l; pack bf16; sP round-trip (same-wave rows)
#pragma unroll
        for (int h = 0; h < 2; ++h) {
            const int prow = wave * WQ + h * 16 + c;
#pragma unroll
            for (int kt = 0; kt < 4; ++kt) {
                float p0 = __builtin_amdgcn_exp2f(st[h][kt][0]);
                float p1 = __builtin_amdgcn_exp2f(st[h][kt][1]);
                float p2 = __builtin_amdgcn_exp2f(st[h][kt][2]);
                float p3 = __builtin_amdgcn_exp2f(st[h][kt][3]);
                lp[h] += (p0 + p1) + (p2 + p3);
                bf16x4 pk;
                pk[0] = (__bf16)p0; pk[1] = (__bf16)p1;
                pk[2] = (__bf16)p2; pk[3] = (__bf16)p3;
                *(bf16x4*)&sP[prow * SPS + kt * 16 + qd * 4] = pk;
            }
        }
        bf16x8 pf[2][2];
#pragma unroll
        for (int h = 0; h < 2; ++h)
#pragma unroll
            for (int ks = 0; ks < 2; ++ks)
                pf[h][ks] = *(const bf16x8*)&sP[(wave * WQ + h * 16 + c) * SPS + ks * 32 + qd * 8];

        // O += P.V
#pragma unroll
        for (int dt = 0; dt < 4; ++dt) {
            const __bf16* vbase = &sV[b][dt * 1024];
            bf16x8 vf0 = *(const bf16x8*)(vbase + koff0);
            bf16x8 vf1 = *(const bf16x8*)(vbase + koff1);
            oacc[0][dt] = __builtin_amdgcn_mfma_f32_16x16x32_bf16(pf[0][0], vf0, oacc[0][dt], 0, 0, 0);
            oacc[0][dt] = __builtin_amdgcn_mfma_f32_16x16x32_bf16(pf[0][1], vf1, oacc[0][dt], 0, 0, 0);
            oacc[1][dt] = __builtin_amdgcn_mfma_f32_16x16x32_bf16(pf[1][0], vf0, oacc[1][dt], 0, 0, 0);
            oacc[1][dt] = __builtin_amdgcn_mfma_f32_16x16x32_bf16(pf[1][1], vf1, oacc[1][dt], 0, 0, 0);
        }
    }

    // ---- epilogue ----
    float lred[2];
#pragma unroll
    for (int h = 0; h < 2; ++h) {
        float l = lp[h];
        l += __shfl_xor(l, 16);
        l += __shfl_xor(l, 32);
        lred[h] = l;
        if (qd == 0) sl[wave * WQ + h * 16 + c] = l;   // same-wave rows
    }
    const int b_ = bh >> 3, hh = bh & 7;

    if (split == 1) {
        // direct normalize + store [B,N,H,D] (round-3 path)
#pragma unroll
        for (int h = 0; h < 2; ++h) {
            floatx4 lf = *(const floatx4*)&sl[wave * WQ + h * 16 + qd * 4];
#pragma unroll
            for (int r = 0; r < 4; ++r) {
                const float inv = 1.f / lf[r];
                const int i = i0 + h * 16 + qd * 4 + r;
                float* orow = Og + (((size_t)b_ * Nc + i) * Hc + hh) * Dc + c;
#pragma unroll
                for (int dt = 0; dt < 4; ++dt)
                    orow[dt * 16] = oacc[h][dt][r] * inv;
            }
        }
    } else {
        // write fp32 partials, then ticket: second finisher combines + stores
        const int pidx = bh * 16 + qt;
        const int pid  = pidx * 2 + kh;
        float* mypart = (float*)(ws + PART_OFF + (size_t)pid * PART_STRIDE);
#pragma unroll
        for (int h = 0; h < 2; ++h)
#pragma unroll
            for (int r = 0; r < 4; ++r) {
                const int row = wave * WQ + h * 16 + qd * 4 + r;
#pragma unroll
                for (int dt = 0; dt < 4; ++dt)
                    mypart[row * 64 + dt * 16 + c] = oacc[h][dt][r];
            }
        if (qd == 0) {
#pragma unroll
            for (int h = 0; h < 2; ++h)
                mypart[8192 + wave * WQ + h * 16 + c] = lred[h];
        }
        __threadfence();                          // release partials (device scope)
        if (tid == 0)
            sflag = (int)atomicAdd((unsigned int*)(ws + TICKET_OFF) + pidx, 1u);
        __syncthreads();
        if (sflag == 1) {                         // partner already published
            __threadfence();                      // acquire partner's partials
            const float* op = (const float*)(ws + PART_OFF + (size_t)(pid ^ 1) * PART_STRIDE);
#pragma unroll
            for (int h = 0; h < 2; ++h) {
                floatx4 lf  = *(const floatx4*)&sl[wave * WQ + h * 16 + qd * 4];
                floatx4 lpf = *(const floatx4*)&op[8192 + wave * WQ + h * 16 + qd * 4];
#pragma unroll
                for (int r = 0; r < 4; ++r) {
                    const float inv = 1.f / (lf[r] + lpf[r]);
                    const int row = wave * WQ + h * 16 + qd * 4 + r;
                    const int i = qt * BQ + row;
                    float* orow = Og + (((size_t)b_ * Nc + i) * Hc + hh) * Dc + c;
#pragma unroll
                    for (int dt = 0; dt < 4; ++dt)
                        orow[dt * 16] = (oacc[h][dt][r] + op[row * 64 + dt * 16 + c]) * inv;
                }
            }
        }
    }
}

extern "C" void kernel_launch(void* const* d_in, const int* in_sizes, int n_in,
                              void* d_out, int out_size, void* d_ws, size_t ws_size,
                              hipStream_t stream) {
    const float* q = (const float*)d_in[0];
    const float* k = (const float*)d_in[1];
    const float* v = (const float*)d_in[2];
    float* out = (float*)d_out;
    char* ws = (char*)d_ws;
    const int split = (ws_size >= WS_NEED) ? 2 : 1;
    if (split == 2)
        hipMemsetAsync(ws + TICKET_OFF, 0, 4096, stream);   // zero tickets (graph-safe)
    prep_kernel<<<dim3(NT, Bc * Hc), 256, 0, stream>>>(k, v, ws);
    attn_kernel<<<dim3(Nc / BQ, Bc * Hc, split), 256, 0, stream>>>(q, ws, out, split);
}

// Round 9
// 137.246 us; speedup vs baseline: 2.3871x; 2.3871x over previous
//
#include <hip/hip_runtime.h>

typedef __bf16 bf16x4 __attribute__((ext_vector_type(4)));
typedef __bf16 bf16x8 __attribute__((ext_vector_type(8)));
typedef float floatx4 __attribute__((ext_vector_type(4)));

constexpr int Bc = 4, Hc = 8, Nc = 2048, Dc = 64;
constexpr int BQ = 128;      // q-rows per block
constexpr int WQ = 32;       // q-rows per wave
constexpr int TK = 64;       // keys per tile
constexpr int NT = Nc / TK;  // 32 tiles
constexpr int SPS = 72;      // sP row stride (bf16)
constexpr float LOG2E = 1.44269504088896340736f;

// ws layout (~17.04 MB):
//   Ksw: [bh][jt] 8 KiB image, chunk g = key*8 + (kc ^ (key&7)) = K[key][kc*8..+7] bf16
//   Vsw: [bh][jt] 8 KiB image, chunk g = d*8   + (kc ^ (d&7))   = V^T[d][kc*8..+7] bf16
//   kkn: [bh][key] fp32 = -(sum K^2)*0.125*log2e
constexpr size_t KSW_OFF = 0;
constexpr size_t VSW_OFF = (size_t)32 * NT * 8192;   // 8 MiB
constexpr size_t KKN_OFF = VSW_OFF * 2;              // 16 MiB

typedef __attribute__((address_space(1))) const unsigned int gu32;
typedef __attribute__((address_space(3))) unsigned int lu32;
__device__ __forceinline__ void dma16(const void* g, void* l) {
    __builtin_amdgcn_global_load_lds((gu32*)g, (lu32*)l, 16, 0, 0);
}
__device__ __forceinline__ void dma4(const void* g, void* l) {
    __builtin_amdgcn_global_load_lds((gu32*)g, (lu32*)l, 4, 0, 0);
}

// ---------------- prep v2 (verified round 5): fully-coalesced image builder ----------------
__global__ __launch_bounds__(256) void prep_kernel(
    const float* __restrict__ Kg, const float* __restrict__ Vg, char* __restrict__ ws)
{
    __shared__ float sT[64 * 68];   // V tile [key][d], stride 68
    const int tid = threadIdx.x;
    const int jt = blockIdx.x, bh = blockIdx.y;

    __bf16* Ksw = (__bf16*)(ws + KSW_OFF) + ((size_t)bh * NT + jt) * 4096;
    __bf16* Vsw = (__bf16*)(ws + VSW_OFF) + ((size_t)bh * NT + jt) * 4096;
    float*  kkn = (float*)(ws + KKN_OFF) + (size_t)bh * Nc + jt * 64;
    const size_t tb = ((size_t)bh * Nc + jt * 64) * Dc;

#pragma unroll
    for (int cc = 0; cc < 2; ++cc) {
        const int g   = tid + cc * 256;
        const int key = g >> 3, kcx = g & 7;
        const int kc  = kcx ^ (key & 7);
        const float* src = Kg + tb + key * 64 + kc * 8;
        float4 a = *(const float4*)src;
        float4 b = *(const float4*)(src + 4);
        float ss = a.x*a.x + a.y*a.y + a.z*a.z + a.w*a.w
                 + b.x*b.x + b.y*b.y + b.z*b.z + b.w*b.w;
        ss += __shfl_xor(ss, 1);
        ss += __shfl_xor(ss, 2);
        ss += __shfl_xor(ss, 4);
        if (kcx == 0) kkn[key] = -(ss * 0.125f * LOG2E);
        bf16x8 c8;
        c8[0]=(__bf16)a.x; c8[1]=(__bf16)a.y; c8[2]=(__bf16)a.z; c8[3]=(__bf16)a.w;
        c8[4]=(__bf16)b.x; c8[5]=(__bf16)b.y; c8[6]=(__bf16)b.z; c8[7]=(__bf16)b.w;
        *(bf16x8*)(Ksw + g * 8) = c8;
    }
    {
        const int js = tid >> 2, dc = (tid & 3) * 16;
        const float* vr = Vg + tb + js * 64 + dc;
        float* dst = &sT[js * 68 + dc];
        *(float4*)dst       = *(const float4*)vr;
        *(float4*)(dst + 4) = *(const float4*)(vr + 4);
        *(float4*)(dst + 8) = *(const float4*)(vr + 8);
        *(float4*)(dst + 12)= *(const float4*)(vr + 12);
    }
    __syncthreads();
#pragma unroll
    for (int cc = 0; cc < 2; ++cc) {
        const int g = tid + cc * 256;
        const int d = g >> 3, kcx = g & 7;
        const int kc = kcx ^ (d & 7);
        bf16x8 c8;
#pragma unroll
        for (int e = 0; e < 8; ++e) {
            const int ee = (e + kcx) & 7;
            c8[ee] = (__bf16)sT[(kc * 8 + ee) * 68 + d];
        }
        *(bf16x8*)(Vsw + g * 8) = c8;
    }
}

// ---------------- main fused attention: S/PV software pipeline ----------------
// logits*log2e = (2qk - kk)/8*log2e; qq cancels. exp2-domain, no max-sub
// (bounded args). Q pre-scaled 0.25*log2e; -kk*log2e/8 is the acc init.
// Pipeline: at iter jt, MFMA-pipe runs S^T(jt) AND PV(jt-1) (P in regs,
// V(jt-1) in a triple-buffered LDS slot) while trans/VALU run exp2(jt)+pack.
__global__ __launch_bounds__(256, 2) void attn_kernel(
    const float* __restrict__ Qg, const char* __restrict__ ws, float* __restrict__ Og)
{
    __shared__ __align__(16) __bf16 sK[2][4096];
    __shared__ __align__(16) __bf16 sVall[3 * 4096];   // triple-buffered V image
    __shared__ __align__(16) float  skk[2][64];
    __shared__ __align__(16) __bf16 sP[BQ * SPS];
    __shared__ __align__(16) float  sl[BQ];

    const int tid  = threadIdx.x;
    const int wave = tid >> 6;
    const int lane = tid & 63;
    const int qd   = lane >> 4;
    const int c    = lane & 15;

    const int qt = blockIdx.x;    // 0..15
    const int bh = blockIdx.y;    // 0..31

    const char* Kimg = ws + KSW_OFF + (size_t)bh * NT * 8192;
    const char* Vimg = ws + VSW_OFF + (size_t)bh * NT * 8192;
    const float* kkp = (const float*)(ws + KKN_OFF) + (size_t)bh * Nc;

    const float qscale = 0.25f * LOG2E;
    const int i0 = qt * BQ + wave * WQ;

    // Q fragments (B-operand): qf[h][ks] = Q[i0+h*16+c][ks*32+qd*8+j]*qscale
    bf16x8 qf[2][2];
#pragma unroll
    for (int h = 0; h < 2; ++h) {
        const float* qrow = Qg + ((size_t)bh * Nc + i0 + h * 16 + c) * Dc + qd * 8;
#pragma unroll
        for (int ks = 0; ks < 2; ++ks) {
            float4 a = *(const float4*)(qrow + ks * 32);
            float4 b = *(const float4*)(qrow + ks * 32 + 4);
            bf16x8 f;
            f[0] = (__bf16)(a.x * qscale); f[1] = (__bf16)(a.y * qscale);
            f[2] = (__bf16)(a.z * qscale); f[3] = (__bf16)(a.w * qscale);
            f[4] = (__bf16)(b.x * qscale); f[5] = (__bf16)(b.y * qscale);
            f[6] = (__bf16)(b.z * qscale); f[7] = (__bf16)(b.w * qscale);
            qf[h][ks] = f;
        }
    }

    // fragment elem offsets into an 8KiB image (same for sK and sV)
    const int koff0 = c * 64 + ((qd ^ (c & 7)) << 3);         // ks=0
    const int koff1 = c * 64 + (((4 + qd) ^ (c & 7)) << 3);   // ks=1

    floatx4 oacc[2][4];
#pragma unroll
    for (int h = 0; h < 2; ++h)
#pragma unroll
        for (int dt = 0; dt < 4; ++dt)
#pragma unroll
            for (int e = 0; e < 4; ++e) oacc[h][dt][e] = 0.f;
    float lp[2] = {0.f, 0.f};

    // V triple-buffer rotation (no %3 in the hot loop)
    __bf16* vprev = &sVall[2 * 4096];   // unused at jt=0 (PV guarded)
    __bf16* vcur  = &sVall[0];
    __bf16* vnext = &sVall[1 * 4096];

    auto stage = [&](int jt2, int kb, __bf16* vdst) {
        const char* ki = Kimg + (size_t)jt2 * 8192;
        const char* vi = Vimg + (size_t)jt2 * 8192;
#pragma unroll
        for (int i = 0; i < 2; ++i) {
            const int off    = wave * 2048 + i * 1024 + lane * 16;
            const int ldsoff = wave * 2048 + i * 1024;
            dma16(ki + off, (char*)&sK[kb][0] + ldsoff);
            dma16(vi + off, (char*)vdst + ldsoff);
        }
        if (wave == 3) dma4(kkp + jt2 * 64 + lane, &skk[kb][0]);
    };

    stage(0, 0, vcur);

    bf16x8 pfp[2][2];   // P(jt-1) in A-layout registers

    for (int jt = 0; jt < NT; ++jt) {
        const int b = jt & 1;
        __syncthreads();                             // staged(jt) visible
        if (jt + 1 < NT) stage(jt + 1, b ^ 1, vnext);

        // S^T(jt) = K.Q^T with acc init = -kk*scale (bias folded in)
        floatx4 st[2][4];
#pragma unroll
        for (int kt = 0; kt < 4; ++kt) {
            floatx4 kkf = *(const floatx4*)&skk[b][kt * 16 + qd * 4];
            st[0][kt] = kkf; st[1][kt] = kkf;
        }
#pragma unroll
        for (int kt = 0; kt < 4; ++kt) {
            const __bf16* kbase = &sK[b][kt * 1024];
            bf16x8 kf0 = *(const bf16x8*)(kbase + koff0);
            bf16x8 kf1 = *(const bf16x8*)(kbase + koff1);
            st[0][kt] = __builtin_amdgcn_mfma_f32_16x16x32_bf16(kf0, qf[0][0], st[0][kt], 0, 0, 0);
            st[0][kt] = __builtin_amdgcn_mfma_f32_16x16x32_bf16(kf1, qf[0][1], st[0][kt], 0, 0, 0);
            st[1][kt] = __builtin_amdgcn_mfma_f32_16x16x32_bf16(kf0, qf[1][0], st[1][kt], 0, 0, 0);
            st[1][kt] = __builtin_amdgcn_mfma_f32_16x16x32_bf16(kf1, qf[1][1], st[1][kt], 0, 0, 0);
        }

        // PV(jt-1): independent of S(jt)/exp2(jt) — fills the MFMA pipe while
        // the trans/VALU pipes run exp2+pack below (compiler interleaves).
        if (jt > 0) {
#pragma unroll
            for (int dt = 0; dt < 4; ++dt) {
                const __bf16* vbase = vprev + dt * 1024;
                bf16x8 vf0 = *(const bf16x8*)(vbase + koff0);
                bf16x8 vf1 = *(const bf16x8*)(vbase + koff1);
                oacc[0][dt] = __builtin_amdgcn_mfma_f32_16x16x32_bf16(pfp[0][0], vf0, oacc[0][dt], 0, 0, 0);
                oacc[0][dt] = __builtin_amdgcn_mfma_f32_16x16x32_bf16(pfp[0][1], vf1, oacc[0][dt], 0, 0, 0);
                oacc[1][dt] = __builtin_amdgcn_mfma_f32_16x16x32_bf16(pfp[1][0], vf0, oacc[1][dt], 0, 0, 0);
                oacc[1][dt] = __builtin_amdgcn_mfma_f32_16x16x32_bf16(pfp[1][1], vf1, oacc[1][dt], 0, 0, 0);
            }
        }

        // p = exp2(st); accumulate l; pack bf16; sP round-trip (same-wave rows)
#pragma unroll
        for (int h = 0; h < 2; ++h) {
            const int prow = wave * WQ + h * 16 + c;
#pragma unroll
            for (int kt = 0; kt < 4; ++kt) {
                float p0 = __builtin_amdgcn_exp2f(st[h][kt][0]);
                float p1 = __builtin_amdgcn_exp2f(st[h][kt][1]);
                float p2 = __builtin_amdgcn_exp2f(st[h][kt][2]);
                float p3 = __builtin_amdgcn_exp2f(st[h][kt][3]);
                lp[h] += (p0 + p1) + (p2 + p3);
                bf16x4 pk;
                pk[0] = (__bf16)p0; pk[1] = (__bf16)p1;
                pk[2] = (__bf16)p2; pk[3] = (__bf16)p3;
                *(bf16x4*)&sP[prow * SPS + kt * 16 + qd * 4] = pk;
            }
        }
        // P(jt) back in A-layout registers for next iteration's PV
#pragma unroll
        for (int h = 0; h < 2; ++h)
#pragma unroll
            for (int ks = 0; ks < 2; ++ks)
                pfp[h][ks] = *(const bf16x8*)&sP[(wave * WQ + h * 16 + c) * SPS + ks * 32 + qd * 8];

        // rotate V buffers: prev<-cur, cur<-next, next<-old prev
        __bf16* t = vprev; vprev = vcur; vcur = vnext; vnext = t;
    }

    // drain: PV(NT-1)
#pragma unroll
    for (int dt = 0; dt < 4; ++dt) {
        const __bf16* vbase = vprev + dt * 1024;
        bf16x8 vf0 = *(const bf16x8*)(vbase + koff0);
        bf16x8 vf1 = *(const bf16x8*)(vbase + koff1);
        oacc[0][dt] = __builtin_amdgcn_mfma_f32_16x16x32_bf16(pfp[0][0], vf0, oacc[0][dt], 0, 0, 0);
        oacc[0][dt] = __builtin_amdgcn_mfma_f32_16x16x32_bf16(pfp[0][1], vf1, oacc[0][dt], 0, 0, 0);
        oacc[1][dt] = __builtin_amdgcn_mfma_f32_16x16x32_bf16(pfp[1][0], vf0, oacc[1][dt], 0, 0, 0);
        oacc[1][dt] = __builtin_amdgcn_mfma_f32_16x16x32_bf16(pfp[1][1], vf1, oacc[1][dt], 0, 0, 0);
    }

    // Epilogue: l via quad butterfly, normalize, store [B,N,H,D]
#pragma unroll
    for (int h = 0; h < 2; ++h) {
        float l = lp[h];
        l += __shfl_xor(l, 16);
        l += __shfl_xor(l, 32);
        if (qd == 0) sl[wave * WQ + h * 16 + c] = l;
    }
    const int b_ = bh >> 3, hh = bh & 7;
#pragma unroll
    for (int h = 0; h < 2; ++h) {
        floatx4 lf = *(const floatx4*)&sl[wave * WQ + h * 16 + qd * 4];
#pragma unroll
        for (int r = 0; r < 4; ++r) {
            const float inv = 1.f / lf[r];
            const int i = i0 + h * 16 + qd * 4 + r;
            float* orow = Og + (((size_t)b_ * Nc + i) * Hc + hh) * Dc + c;
#pragma unroll
            for (int dt = 0; dt < 4; ++dt)
                orow[dt * 16] = oacc[h][dt][r] * inv;
        }
    }
}

extern "C" void kernel_launch(void* const* d_in, const int* in_sizes, int n_in,
                              void* d_out, int out_size, void* d_ws, size_t ws_size,
                              hipStream_t stream) {
    const float* q = (const float*)d_in[0];
    const float* k = (const float*)d_in[1];
    const float* v = (const float*)d_in[2];
    float* out = (float*)d_out;
    char* ws = (char*)d_ws;   // ~17.04 MB
    prep_kernel<<<dim3(NT, Bc * Hc), 256, 0, stream>>>(k, v, ws);
    attn_kernel<<<dim3(Nc / BQ, Bc * Hc), 256, 0, stream>>>(q, ws, out);
}